// Round 2
// baseline (537.428 us; speedup 1.0000x reference)
//
#include <hip/hip_runtime.h>
#include <math.h>

// pix_attn, restructured (R1):
//  - u-trick:  lg_raw[t] = sum_c xs[t,c] * u_c,  u = W_k^h · q   (no k vectors)
//  - y-trick:  x_fusion = sum_c y_c * W_v[c,:] + (sum_t p'_t)*b_v,
//              y_c = sum_t p'_t xs[t,c],  p'_t = p_t + p_g/9  (global token folded)
//  - tile 4x16 (stride-24 padded LDS: exact 2-way banks = free; 64B coalesced stores)
//  - 512-thread blocks, wave = head -> 16 waves/CU
//  - lg/y loops fully unrolled: scramble offsets are compile-time ds_read immediates
//
// Scramble: f = t*64 + c  ->  ch = f/9, l = f%9, (wi,wj) = (l/3, l%3)
// qk cols: q = h*8+d, q_ = 64+h*8+d ; kv cols: k = h*8+d, v = 64+h*8+d

#define XS  24      // padded row stride (floats)
#define CHS 144     // per-channel tile stride = 6 rows * 24

__global__ __launch_bounds__(512, 4) void pix_attn_main(
    const float* __restrict__ x,
    const float* __restrict__ W_qk,
    const float* __restrict__ b_qk,
    const float* __restrict__ W_kv,
    const float* __restrict__ b_kv,
    const float* __restrict__ W_proj,
    const float* __restrict__ b_proj,
    float* __restrict__ out)
{
    __shared__ float xt[64 * CHS];     // 36864 B : [ch][6 rows][24]
    __shared__ float pre_s[64 * 65];   // 16640 B : [pixel][65] (stride-65: 2-way)

    const int tid  = threadIdx.x;
    const int blk  = blockIdx.x;
    const int bb   = blk >> 6;               // image
    const int t_id = blk & 63;               // 16 row-tiles x 4 col-tiles
    const int h0   = (t_id >> 2) << 2;       // tile row origin (step 4)
    const int w0   = (t_id & 3) << 4;        // tile col origin (step 16)

    // ---- stage x tile (6 rows x 18 cols halo per channel, reflect pad) ----
    const float* xb = x + (size_t)bb * (64 * 64 * 64);
    for (int idx = tid; idx < 64 * 6 * 18; idx += 512) {
        int ch  = idx / 108;
        int rem = idx - ch * 108;
        int r   = rem / 18;
        int cc  = rem - r * 18;
        int gr  = h0 + r - 1;
        gr = (gr < 0) ? 1 : ((gr > 63) ? 62 : gr);
        int gc  = w0 + cc - 1;
        gc = (gc < 0) ? 1 : ((gc > 63) ? 62 : gc);
        xt[ch * CHS + r * XS + cc] = xb[(ch << 12) + (gr << 6) + gc];
    }
    __syncthreads();

    const int h    = __builtin_amdgcn_readfirstlane(tid >> 6);  // wave = head
    const int h8   = h << 3;
    const int lane = tid & 63;
    const int tr   = lane >> 4;      // 0..3
    const int tc   = lane & 15;      // 0..15
    const float* xl = xt + tr * XS + tc;   // lane base; window reads are +const
    const float scale = 0.35355339059327373f;  // 8^-0.5

    // ---- q / q_ projection (center pixel = +XS+1 from lane base) ----
    float q[8], qp[8];
#pragma unroll
    for (int d = 0; d < 8; ++d) {
        q[d]  = b_qk[h8 + d];
        qp[d] = b_qk[64 + h8 + d];
    }
#pragma unroll
    for (int c = 0; c < 64; ++c) {
        float a = xl[c * CHS + XS + 1];
        const float* w = W_qk + (c << 7) + h8;
#pragma unroll
        for (int d = 0; d < 8; ++d) {
            q[d]  = fmaf(a, w[d], q[d]);
            qp[d] = fmaf(a, w[64 + d], qp[d]);
        }
    }
    float qv = 0.f;
#pragma unroll
    for (int d = 0; d < 8; ++d) qv = fmaf(q[d], qp[d], qv);

    // ---- u = W_k^h · q  (64 values, register array) ; beta = q·b_k ----
    float u[64];
#pragma unroll
    for (int c = 0; c < 64; ++c) {
        const float* w = W_kv + (c << 7) + h8;
        float s = q[0] * w[0];
#pragma unroll
        for (int d = 1; d < 8; ++d) s = fmaf(q[d], w[d], s);
        u[c] = s;
    }
    float beta = 0.f;
#pragma unroll
    for (int d = 0; d < 8; ++d) beta = fmaf(q[d], b_kv[h8 + d], beta);

    // ---- logits: lg_raw[t] = sum_c xs[t,c]*u[c]  (fully unrolled, imm offsets)
    float lgA[9], lgB[9];
#pragma unroll
    for (int t = 0; t < 9; ++t) { lgA[t] = 0.f; lgB[t] = 0.f; }
#pragma unroll
    for (int f = 0; f < 576; ++f) {
        const int t  = f >> 6;
        const int c  = f & 63;
        const int ch = f / 9;
        const int l  = f - ch * 9;
        const int wi = l / 3;
        const int wj = l - wi * 3;
        float a = xl[ch * CHS + wi * XS + wj];
        if (c < 32) lgA[t] = fmaf(a, u[c], lgA[t]);
        else        lgB[t] = fmaf(a, u[c], lgB[t]);
    }

    // ---- softmax over {9 tokens, global, qv} ----
    float lg[11];
    float lgsum = 0.f;
#pragma unroll
    for (int t = 0; t < 9; ++t) {
        float r = lgA[t] + lgB[t];
        lgsum += r;
        lg[t] = (r + beta) * scale;
    }
    lg[9]  = (lgsum * (1.f / 9.f) + beta) * scale;
    lg[10] = qv;
    float m = lg[0];
#pragma unroll
    for (int i = 1; i < 11; ++i) m = fmaxf(m, lg[i]);
    float p[11], denom = 0.f;
#pragma unroll
    for (int i = 0; i < 11; ++i) { p[i] = __expf(lg[i] - m); denom += p[i]; }
    float inv = 1.f / denom;
    float pn[9], Pn = 0.f;
#pragma unroll
    for (int t = 0; t < 9; ++t) {
        pn[t] = (p[t] + p[9] * (1.f / 9.f)) * inv;
        Pn += pn[t];
    }
    const float pqv = p[10] * inv;

    // ---- y_c = sum_t pn[t]*xs[t,c]  (second unrolled scan) ----
    float y[64];
#pragma unroll
    for (int c = 0; c < 64; ++c) y[c] = 0.f;
#pragma unroll
    for (int f = 0; f < 576; ++f) {
        const int t  = f >> 6;
        const int c  = f & 63;
        const int ch = f / 9;
        const int l  = f - ch * 9;
        const int wi = l / 3;
        const int wj = l - wi * 3;
        float a = xl[ch * CHS + wi * XS + wj];
        y[c] = fmaf(pn[t], a, y[c]);
    }

    // ---- head output: o = W_v^T y + Pn*b_v + pqv*q_ ; write to pre_s ----
    float o[8];
#pragma unroll
    for (int d = 0; d < 8; ++d)
        o[d] = fmaf(pqv, qp[d], Pn * b_kv[64 + h8 + d]);
#pragma unroll
    for (int c = 0; c < 64; ++c) {
        const float* w = W_kv + (c << 7) + 64 + h8;
#pragma unroll
        for (int d = 0; d < 8; ++d) o[d] = fmaf(y[c], w[d], o[d]);
    }
#pragma unroll
    for (int d = 0; d < 8; ++d) pre_s[lane * 65 + h8 + d] = o[d];
    __syncthreads();

    // ---- output projection: wave h handles channels h*8..h*8+7, lane = pixel
    const int j0 = h8;
    float o2[8];
#pragma unroll
    for (int j = 0; j < 8; ++j) o2[j] = b_proj[j0 + j];
#pragma unroll
    for (int c = 0; c < 64; ++c) {
        float a = pre_s[lane * 65 + c];
        const float* w = W_proj + (c << 6) + j0;
#pragma unroll
        for (int j = 0; j < 8; ++j) o2[j] = fmaf(a, w[j], o2[j]);
    }
    float* ob = out + (size_t)bb * (64 * 64 * 64);
    const int pr = h0 + tr, pc = w0 + tc;
#pragma unroll
    for (int j = 0; j < 8; ++j)
        ob[((j0 + j) << 12) + (pr << 6) + pc] = o2[j];
}

extern "C" void kernel_launch(void* const* d_in, const int* in_sizes, int n_in,
                              void* d_out, int out_size, void* d_ws, size_t ws_size,
                              hipStream_t stream)
{
    const float* x      = (const float*)d_in[0];
    const float* W_qk   = (const float*)d_in[1];
    const float* b_qk   = (const float*)d_in[2];
    const float* W_kv   = (const float*)d_in[3];
    const float* b_kv   = (const float*)d_in[4];
    const float* W_proj = (const float*)d_in[5];
    const float* b_proj = (const float*)d_in[6];
    float* out = (float*)d_out;

    pix_attn_main<<<512, 512, 0, stream>>>(x, W_qk, b_qk, W_kv, b_kv,
                                           W_proj, b_proj, out);
}

// Round 3
// 400.892 us; speedup vs baseline: 1.3406x; 1.3406x over previous
//
#include <hip/hip_runtime.h>
#include <math.h>

// pix_attn R2: R1 algorithm (u-trick + y-trick, 4x FLOP cut) with register
// pressure fixed.
//  - u-trick:  lg_raw[t] = sum_c xs[t,c] * u_c,  u = W_k^h · q   (no k vectors)
//  - y-trick:  x_fusion = sum_c y_c * W_v[c,:] + (sum p')*b_v,
//              y_c = sum_t p'_t xs[t,c],  p'_t = p_t + p_g/9
//  - launch_bounds(512,3): VGPR cap ~168 (R1's (512,4) forced 64 -> spill storm)
//  - sched_barrier(0) between phases: keeps u[64] / y[64] live ranges disjoint
//  - scans ordered by channel: 9 window reads per ch merge into b64/b96 ds_reads
//  - tile 4x16, stride-24 LDS (exact 2-way banks = free), 64B coalesced stores
//
// Scramble: f = t*64 + c  <->  ch = f/9, l = f%9, (wi,wj) = (l/3, l%3)

#define XS  24      // padded row stride (floats)
#define CHS 144     // per-channel tile stride = 6 rows * 24

__global__ __launch_bounds__(512, 3) void pix_attn_main(
    const float* __restrict__ x,
    const float* __restrict__ W_qk,
    const float* __restrict__ b_qk,
    const float* __restrict__ W_kv,
    const float* __restrict__ b_kv,
    const float* __restrict__ W_proj,
    const float* __restrict__ b_proj,
    float* __restrict__ out)
{
    __shared__ float xt[64 * CHS];     // 36864 B : [ch][6 rows][24]
    __shared__ float pre_s[64 * 65];   // 16640 B : [pixel][65]

    const int tid  = threadIdx.x;
    const int blk  = blockIdx.x;
    const int bb   = blk >> 6;               // image
    const int t_id = blk & 63;               // 16 row-tiles x 4 col-tiles
    const int h0   = (t_id >> 2) << 2;       // tile row origin (step 4)
    const int w0   = (t_id & 3) << 4;        // tile col origin (step 16)

    // ---- stage x tile (6 rows x 18 cols halo per channel, reflect pad) ----
    const float* xb = x + (size_t)bb * (64 * 64 * 64);
    for (int idx = tid; idx < 64 * 6 * 18; idx += 512) {
        int ch  = idx / 108;
        int rem = idx - ch * 108;
        int r   = rem / 18;
        int cc  = rem - r * 18;
        int gr  = h0 + r - 1;
        gr = (gr < 0) ? 1 : ((gr > 63) ? 62 : gr);
        int gc  = w0 + cc - 1;
        gc = (gc < 0) ? 1 : ((gc > 63) ? 62 : gc);
        xt[ch * CHS + r * XS + cc] = xb[(ch << 12) + (gr << 6) + gc];
    }
    __syncthreads();

    const int h    = __builtin_amdgcn_readfirstlane(tid >> 6);  // wave = head
    const int h8   = h << 3;
    const int lane = tid & 63;
    const int tr   = lane >> 4;      // 0..3
    const int tc   = lane & 15;      // 0..15
    const float* xl = xt + tr * XS + tc;       // lane base, reads at +imm
    const float scale = 0.35355339059327373f;  // 8^-0.5

    // ---- Phase A: q / q_ projection (center pixel = +XS+1) ----
    float q[8], qp[8];
#pragma unroll
    for (int d = 0; d < 8; ++d) {
        q[d]  = b_qk[h8 + d];
        qp[d] = b_qk[64 + h8 + d];
    }
#pragma unroll
    for (int c = 0; c < 64; ++c) {
        float a = xl[c * CHS + XS + 1];
        const float* w = W_qk + (c << 7) + h8;
#pragma unroll
        for (int d = 0; d < 8; ++d) {
            q[d]  = fmaf(a, w[d], q[d]);
            qp[d] = fmaf(a, w[64 + d], qp[d]);
        }
    }
    float qv = 0.f;
#pragma unroll
    for (int d = 0; d < 8; ++d) qv = fmaf(q[d], qp[d], qv);
    __builtin_amdgcn_sched_barrier(0);

    // ---- Phase B: u = W_k^h · q ; beta = q · b_k ----
    float u[64];
#pragma unroll
    for (int c = 0; c < 64; ++c) {
        const float* w = W_kv + (c << 7) + h8;
        float s = q[0] * w[0];
#pragma unroll
        for (int d = 1; d < 8; ++d) s = fmaf(q[d], w[d], s);
        u[c] = s;
    }
    float beta = 0.f;
#pragma unroll
    for (int d = 0; d < 8; ++d) beta = fmaf(q[d], b_kv[h8 + d], beta);
    __builtin_amdgcn_sched_barrier(0);

    // ---- Phase C: logits, scanned by channel (merged window reads) ----
    float lgA[9], lgB[9];
#pragma unroll
    for (int t = 0; t < 9; ++t) { lgA[t] = 0.f; lgB[t] = 0.f; }
#pragma unroll
    for (int ch = 0; ch < 64; ++ch) {
#pragma unroll
        for (int l = 0; l < 9; ++l) {
            const int f  = ch * 9 + l;
            const int t  = f >> 6;
            const int c  = f & 63;
            const int wi = l / 3;
            const int wj = l - wi * 3;
            float a = xl[ch * CHS + wi * XS + wj];
            if (f & 1) lgB[t] = fmaf(a, u[c], lgB[t]);
            else       lgA[t] = fmaf(a, u[c], lgA[t]);
        }
    }
    __builtin_amdgcn_sched_barrier(0);

    // ---- Phase D: softmax over {9 tokens, global, qv} ----
    float lg[11];
    float lgsum = 0.f;
#pragma unroll
    for (int t = 0; t < 9; ++t) {
        float r = lgA[t] + lgB[t];
        lgsum += r;
        lg[t] = (r + beta) * scale;
    }
    lg[9]  = (lgsum * (1.f / 9.f) + beta) * scale;
    lg[10] = qv;
    float m = lg[0];
#pragma unroll
    for (int i = 1; i < 11; ++i) m = fmaxf(m, lg[i]);
    float p[11], denom = 0.f;
#pragma unroll
    for (int i = 0; i < 11; ++i) { p[i] = __expf(lg[i] - m); denom += p[i]; }
    float inv = 1.f / denom;
    float pn[9], Pn = 0.f;
#pragma unroll
    for (int t = 0; t < 9; ++t) {
        pn[t] = (p[t] + p[9] * (1.f / 9.f)) * inv;
        Pn += pn[t];
    }
    const float pqv = p[10] * inv;
    __builtin_amdgcn_sched_barrier(0);

    // ---- Phase E: y_c = sum_t pn[t]*xs[t,c], scanned by channel ----
    float y[64];
#pragma unroll
    for (int c = 0; c < 64; ++c) y[c] = 0.f;
#pragma unroll
    for (int ch = 0; ch < 64; ++ch) {
#pragma unroll
        for (int l = 0; l < 9; ++l) {
            const int f  = ch * 9 + l;
            const int t  = f >> 6;
            const int c  = f & 63;
            const int wi = l / 3;
            const int wj = l - wi * 3;
            float a = xl[ch * CHS + wi * XS + wj];
            y[c] = fmaf(pn[t], a, y[c]);
        }
    }
    __builtin_amdgcn_sched_barrier(0);

    // ---- Phase F: o = W_v^T y + Pn*b_v + pqv*q_ ----
    float oA[8], oB[8];
#pragma unroll
    for (int d = 0; d < 8; ++d) {
        oA[d] = fmaf(pqv, qp[d], Pn * b_kv[64 + h8 + d]);
        oB[d] = 0.f;
    }
#pragma unroll
    for (int c = 0; c < 64; ++c) {
        const float* w = W_kv + (c << 7) + 64 + h8;
#pragma unroll
        for (int d = 0; d < 8; ++d) {
            if (c & 1) oB[d] = fmaf(y[c], w[d], oB[d]);
            else       oA[d] = fmaf(y[c], w[d], oA[d]);
        }
    }
#pragma unroll
    for (int d = 0; d < 8; ++d) pre_s[lane * 65 + h8 + d] = oA[d] + oB[d];
    __syncthreads();

    // ---- Phase G: output projection; wave h -> channels h8..h8+7 ----
    const int j0 = h8;
    float o2[8];
#pragma unroll
    for (int j = 0; j < 8; ++j) o2[j] = b_proj[j0 + j];
#pragma unroll
    for (int c = 0; c < 64; ++c) {
        float a = pre_s[lane * 65 + c];
        const float* w = W_proj + (c << 6) + j0;
#pragma unroll
        for (int j = 0; j < 8; ++j) o2[j] = fmaf(a, w[j], o2[j]);
    }
    float* ob = out + (size_t)bb * (64 * 64 * 64);
    const int pr = h0 + tr, pc = w0 + tc;
#pragma unroll
    for (int j = 0; j < 8; ++j)
        ob[((j0 + j) << 12) + (pr << 6) + pc] = o2[j];
}

extern "C" void kernel_launch(void* const* d_in, const int* in_sizes, int n_in,
                              void* d_out, int out_size, void* d_ws, size_t ws_size,
                              hipStream_t stream)
{
    const float* x      = (const float*)d_in[0];
    const float* W_qk   = (const float*)d_in[1];
    const float* b_qk   = (const float*)d_in[2];
    const float* W_kv   = (const float*)d_in[3];
    const float* b_kv   = (const float*)d_in[4];
    const float* W_proj = (const float*)d_in[5];
    const float* b_proj = (const float*)d_in[6];
    float* out = (float*)d_out;

    pix_attn_main<<<512, 512, 0, stream>>>(x, W_qk, b_qk, W_kv, b_kv,
                                           W_proj, b_proj, out);
}

// Round 4
// 181.586 us; speedup vs baseline: 2.9596x; 2.2077x over previous
//
#include <hip/hip_runtime.h>
#include <math.h>

// pix_attn R3: R1/R2 algorithm (u-trick + y-trick, 4x FLOP cut), register
// pressure restructured to fit the empirical 84-VGPR cap of (512,3).
//  - u-trick:  lg_raw[t] = sum_c xs[t,c] * u_c,  u = W_k^h · q
//  - y-trick:  x_fusion = sum_c y_c * W_v[c,:] + (sum p')*b_v
//  - CHUNKED: u/y processed 16 channels at a time, each chunk's registers die
//    at a sched_barrier(0) fence -> peak live ~70 VGPR (R2's 64-wide arrays
//    peaked ~110 and spilled: 330 MB fetch, 627 MB write of scratch traffic)
//  - tile 4x16, stride-24 LDS (exact 2-way banks = free), 64B coalesced stores
//  - 512 thr/block, wave = head (scalar weight loads); 3 blocks/CU by LDS
//
// Scramble: f = t*64 + c  <->  ch = f/9, l = f%9, (wi,wj) = (l/3, l%3)

#define XS  24      // padded row stride (floats)
#define CHS 144     // per-channel tile stride = 6 rows * 24

__global__ __launch_bounds__(512, 3) void pix_attn_main(
    const float* __restrict__ x,
    const float* __restrict__ W_qk,
    const float* __restrict__ b_qk,
    const float* __restrict__ W_kv,
    const float* __restrict__ b_kv,
    const float* __restrict__ W_proj,
    const float* __restrict__ b_proj,
    float* __restrict__ out)
{
    __shared__ float xt[64 * CHS];     // 36864 B : [ch][6 rows][24]
    __shared__ float pre_s[64 * 65];   // 16640 B : [pixel][65]

    const int tid  = threadIdx.x;
    const int blk  = blockIdx.x;
    const int bb   = blk >> 6;               // image
    const int t_id = blk & 63;               // 16 row-tiles x 4 col-tiles
    const int h0   = (t_id >> 2) << 2;       // tile row origin (step 4)
    const int w0   = (t_id & 3) << 4;        // tile col origin (step 16)

    // ---- stage x tile (6 rows x 18 cols halo per channel, reflect pad) ----
    const float* xb = x + (size_t)bb * (64 * 64 * 64);
    for (int idx = tid; idx < 64 * 6 * 18; idx += 512) {
        int ch  = idx / 108;
        int rem = idx - ch * 108;
        int r   = rem / 18;
        int cc  = rem - r * 18;
        int gr  = h0 + r - 1;
        gr = (gr < 0) ? 1 : ((gr > 63) ? 62 : gr);
        int gc  = w0 + cc - 1;
        gc = (gc < 0) ? 1 : ((gc > 63) ? 62 : gc);
        xt[ch * CHS + r * XS + cc] = xb[(ch << 12) + (gr << 6) + gc];
    }
    __syncthreads();

    const int h    = __builtin_amdgcn_readfirstlane(tid >> 6);  // wave = head
    const int h8   = h << 3;
    const int lane = tid & 63;
    const int tr   = lane >> 4;      // 0..3
    const int tc   = lane & 15;      // 0..15
    const float* xl = xt + tr * XS + tc;       // lane base, reads at +imm
    const float scale = 0.35355339059327373f;  // 8^-0.5

    // ---- Phase A: q / q_ projection (center pixel = +XS+1) ----
    float q[8], qp[8];
#pragma unroll
    for (int d = 0; d < 8; ++d) {
        q[d]  = b_qk[h8 + d];
        qp[d] = b_qk[64 + h8 + d];
    }
#pragma unroll
    for (int c = 0; c < 64; ++c) {
        float a = xl[c * CHS + XS + 1];
        const float* w = W_qk + (c << 7) + h8;
#pragma unroll
        for (int d = 0; d < 8; ++d) {
            q[d]  = fmaf(a, w[d], q[d]);
            qp[d] = fmaf(a, w[64 + d], qp[d]);
        }
    }
    float qv = 0.f;
#pragma unroll
    for (int d = 0; d < 8; ++d) qv = fmaf(q[d], qp[d], qv);
    float beta = 0.f;
#pragma unroll
    for (int d = 0; d < 8; ++d) beta = fmaf(q[d], b_kv[h8 + d], beta);
    __builtin_amdgcn_sched_barrier(0);

    // ---- Phase B+C fused, chunked: u[16] per chunk -> logits scan ----
    float lgA[9], lgB[9];
#pragma unroll
    for (int t = 0; t < 9; ++t) { lgA[t] = 0.f; lgB[t] = 0.f; }
#pragma unroll
    for (int cch = 0; cch < 4; ++cch) {
        float u[16];
#pragma unroll
        for (int ci = 0; ci < 16; ++ci) {
            const int c = cch * 16 + ci;
            const float* w = W_kv + (c << 7) + h8;
            float s = q[0] * w[0];
#pragma unroll
            for (int d = 1; d < 8; ++d) s = fmaf(q[d], w[d], s);
            u[ci] = s;
        }
#pragma unroll
        for (int t = 0; t < 9; ++t) {
#pragma unroll
            for (int ci = 0; ci < 16; ++ci) {
                const int c  = cch * 16 + ci;
                const int f  = t * 64 + c;
                const int ch = f / 9;
                const int l  = f - ch * 9;
                const int wi = l / 3;
                const int wj = l - wi * 3;
                float a = xl[ch * CHS + wi * XS + wj];
                if (f & 1) lgB[t] = fmaf(a, u[ci], lgB[t]);
                else       lgA[t] = fmaf(a, u[ci], lgA[t]);
            }
        }
        __builtin_amdgcn_sched_barrier(0);
    }

    // ---- Phase D: softmax over {9 tokens, global, qv} ----
    float lg[11];
    float lgsum = 0.f;
#pragma unroll
    for (int t = 0; t < 9; ++t) {
        float r = lgA[t] + lgB[t];
        lgsum += r;
        lg[t] = (r + beta) * scale;
    }
    lg[9]  = (lgsum * (1.f / 9.f) + beta) * scale;
    lg[10] = qv;
    float m = lg[0];
#pragma unroll
    for (int i = 1; i < 11; ++i) m = fmaxf(m, lg[i]);
    float p[11], denom = 0.f;
#pragma unroll
    for (int i = 0; i < 11; ++i) { p[i] = __expf(lg[i] - m); denom += p[i]; }
    float inv = 1.f / denom;
    float pn[9], Pn = 0.f;
#pragma unroll
    for (int t = 0; t < 9; ++t) {
        pn[t] = (p[t] + p[9] * (1.f / 9.f)) * inv;
        Pn += pn[t];
    }
    const float pqv = p[10] * inv;
    __builtin_amdgcn_sched_barrier(0);

    // ---- Phase E+F fused, chunked: y[16] per chunk -> fold into o[8] ----
    float o[8];
#pragma unroll
    for (int d = 0; d < 8; ++d)
        o[d] = fmaf(pqv, qp[d], Pn * b_kv[64 + h8 + d]);
#pragma unroll
    for (int cch = 0; cch < 4; ++cch) {
        float y[16];
#pragma unroll
        for (int ci = 0; ci < 16; ++ci) y[ci] = 0.f;
#pragma unroll
        for (int t = 0; t < 9; ++t) {
#pragma unroll
            for (int ci = 0; ci < 16; ++ci) {
                const int c  = cch * 16 + ci;
                const int f  = t * 64 + c;
                const int ch = f / 9;
                const int l  = f - ch * 9;
                const int wi = l / 3;
                const int wj = l - wi * 3;
                float a = xl[ch * CHS + wi * XS + wj];
                y[ci] = fmaf(pn[t], a, y[ci]);
            }
        }
#pragma unroll
        for (int ci = 0; ci < 16; ++ci) {
            const int c = cch * 16 + ci;
            const float* w = W_kv + (c << 7) + 64 + h8;
#pragma unroll
            for (int d = 0; d < 8; ++d) o[d] = fmaf(y[ci], w[d], o[d]);
        }
        __builtin_amdgcn_sched_barrier(0);
    }
#pragma unroll
    for (int d = 0; d < 8; ++d) pre_s[lane * 65 + h8 + d] = o[d];
    __syncthreads();

    // ---- Phase G: output projection; wave h -> channels h8..h8+7 ----
    const int j0 = h8;
    float o2[8];
#pragma unroll
    for (int j = 0; j < 8; ++j) o2[j] = b_proj[j0 + j];
#pragma unroll
    for (int c = 0; c < 64; ++c) {
        float a = pre_s[lane * 65 + c];
        const float* w = W_proj + (c << 6) + j0;
#pragma unroll
        for (int j = 0; j < 8; ++j) o2[j] = fmaf(a, w[j], o2[j]);
    }
    float* ob = out + (size_t)bb * (64 * 64 * 64);
    const int pr = h0 + tr, pc = w0 + tc;
#pragma unroll
    for (int j = 0; j < 8; ++j)
        ob[((j0 + j) << 12) + (pr << 6) + pc] = o2[j];
}

extern "C" void kernel_launch(void* const* d_in, const int* in_sizes, int n_in,
                              void* d_out, int out_size, void* d_ws, size_t ws_size,
                              hipStream_t stream)
{
    const float* x      = (const float*)d_in[0];
    const float* W_qk   = (const float*)d_in[1];
    const float* b_qk   = (const float*)d_in[2];
    const float* W_kv   = (const float*)d_in[3];
    const float* b_kv   = (const float*)d_in[4];
    const float* W_proj = (const float*)d_in[5];
    const float* b_proj = (const float*)d_in[6];
    float* out = (float*)d_out;

    pix_attn_main<<<512, 512, 0, stream>>>(x, W_qk, b_qk, W_kv, b_kv,
                                           W_proj, b_proj, out);
}

// Round 5
// 153.421 us; speedup vs baseline: 3.5030x; 1.1836x over previous
//
#include <hip/hip_runtime.h>
#include <math.h>

// pix_attn R4: u-trick + y-trick (4x FLOP cut) with spill finally killed.
//  - Empirical VGPR cap = 256/min_waves_per_EU: (512,3) capped at 84 and the
//    scheduler's ds_read hoisting (144 reads/fence region) blew past it ->
//    152/274 MB scratch traffic. Now: (512,2) -> 128 cap (grid is 2 blocks/CU
//    anyway, so no occupancy loss), and fences every 4 channels bound the
//    in-flight read window to 36 -> peak live ~80.
//  - u-trick:  lg_raw[t] = sum_c xs[t,c] * u_c,  u = W_k^h · q
//  - y-trick:  x_fusion = sum_c y_c * W_v[c,:] + (sum p')*b_v
//  - tile 4x16, stride-24 LDS (exact 2-way banks = free), 64B coalesced stores
//  - wave = head -> all weight reads are wave-uniform scalar loads
//
// Scramble: f = t*64 + c  <->  ch = f/9, l = f%9, (wi,wj) = (l/3, l%3)

#define XS  24      // padded row stride (floats)
#define CHS 144     // per-channel tile stride = 6 rows * 24

__global__ __launch_bounds__(512, 2) void pix_attn_main(
    const float* __restrict__ x,
    const float* __restrict__ W_qk,
    const float* __restrict__ b_qk,
    const float* __restrict__ W_kv,
    const float* __restrict__ b_kv,
    const float* __restrict__ W_proj,
    const float* __restrict__ b_proj,
    float* __restrict__ out)
{
    __shared__ float xt[64 * CHS];     // 36864 B : [ch][6 rows][24]
    __shared__ float pre_s[64 * 65];   // 16640 B : [pixel][65]

    const int tid  = threadIdx.x;
    const int blk  = blockIdx.x;
    const int bb   = blk >> 6;               // image
    const int t_id = blk & 63;               // 16 row-tiles x 4 col-tiles
    const int h0   = (t_id >> 2) << 2;       // tile row origin (step 4)
    const int w0   = (t_id & 3) << 4;        // tile col origin (step 16)

    // ---- stage x tile (6 rows x 18 cols halo per channel, reflect pad) ----
    const float* xb = x + (size_t)bb * (64 * 64 * 64);
    for (int idx = tid; idx < 64 * 6 * 18; idx += 512) {
        int ch  = idx / 108;
        int rem = idx - ch * 108;
        int r   = rem / 18;
        int cc  = rem - r * 18;
        int gr  = h0 + r - 1;
        gr = (gr < 0) ? 1 : ((gr > 63) ? 62 : gr);
        int gc  = w0 + cc - 1;
        gc = (gc < 0) ? 1 : ((gc > 63) ? 62 : gc);
        xt[ch * CHS + r * XS + cc] = xb[(ch << 12) + (gr << 6) + gc];
    }
    __syncthreads();

    const int h    = __builtin_amdgcn_readfirstlane(tid >> 6);  // wave = head
    const int h8   = h << 3;
    const int lane = tid & 63;
    const int tr   = lane >> 4;      // 0..3
    const int tc   = lane & 15;      // 0..15
    const float* xl = xt + tr * XS + tc;       // lane base, reads at +imm
    const float scale = 0.35355339059327373f;  // 8^-0.5

    // ---- Phase A: q / q_ projection (center pixel = +XS+1) ----
    float q[8], qp[8];
#pragma unroll
    for (int d = 0; d < 8; ++d) {
        q[d]  = b_qk[h8 + d];
        qp[d] = b_qk[64 + h8 + d];
    }
#pragma unroll
    for (int cc2 = 0; cc2 < 2; ++cc2) {
#pragma unroll
        for (int ci = 0; ci < 32; ++ci) {
            const int c = cc2 * 32 + ci;
            float a = xl[c * CHS + XS + 1];
            const float* w = W_qk + (c << 7) + h8;
#pragma unroll
            for (int d = 0; d < 8; ++d) {
                q[d]  = fmaf(a, w[d], q[d]);
                qp[d] = fmaf(a, w[64 + d], qp[d]);
            }
        }
        __builtin_amdgcn_sched_barrier(0);
    }
    float qv = 0.f;
#pragma unroll
    for (int d = 0; d < 8; ++d) qv = fmaf(q[d], qp[d], qv);
    float beta = 0.f;
#pragma unroll
    for (int d = 0; d < 8; ++d) beta = fmaf(q[d], b_kv[h8 + d], beta);
    __builtin_amdgcn_sched_barrier(0);

    // ---- Phase B+C fused, 4-channel chunks: u[4] -> logit scan (36 reads) ----
    float lgA[9], lgB[9];
#pragma unroll
    for (int t = 0; t < 9; ++t) { lgA[t] = 0.f; lgB[t] = 0.f; }
#pragma unroll
    for (int cch = 0; cch < 16; ++cch) {
        float u[4];
#pragma unroll
        for (int ci = 0; ci < 4; ++ci) {
            const int c = cch * 4 + ci;
            const float* w = W_kv + (c << 7) + h8;
            float s = q[0] * w[0];
#pragma unroll
            for (int d = 1; d < 8; ++d) s = fmaf(q[d], w[d], s);
            u[ci] = s;
        }
#pragma unroll
        for (int t = 0; t < 9; ++t) {
#pragma unroll
            for (int ci = 0; ci < 4; ++ci) {
                const int c  = cch * 4 + ci;
                const int f  = t * 64 + c;
                const int ch = f / 9;
                const int l  = f - ch * 9;
                const int wi = l / 3;
                const int wj = l - wi * 3;
                float a = xl[ch * CHS + wi * XS + wj];
                if (c & 1) lgB[t] = fmaf(a, u[ci], lgB[t]);
                else       lgA[t] = fmaf(a, u[ci], lgA[t]);
            }
        }
        __builtin_amdgcn_sched_barrier(0);
    }

    // ---- Phase D: softmax over {9 tokens, global, qv} ----
    float lg[11];
    float lgsum = 0.f;
#pragma unroll
    for (int t = 0; t < 9; ++t) {
        float r = lgA[t] + lgB[t];
        lgsum += r;
        lg[t] = (r + beta) * scale;
    }
    lg[9]  = (lgsum * (1.f / 9.f) + beta) * scale;
    lg[10] = qv;
    float m = lg[0];
#pragma unroll
    for (int i = 1; i < 11; ++i) m = fmaxf(m, lg[i]);
    float p[11], denom = 0.f;
#pragma unroll
    for (int i = 0; i < 11; ++i) { p[i] = __expf(lg[i] - m); denom += p[i]; }
    float inv = 1.f / denom;
    float pn[9], Pn = 0.f;
#pragma unroll
    for (int t = 0; t < 9; ++t) {
        pn[t] = (p[t] + p[9] * (1.f / 9.f)) * inv;
        Pn += pn[t];
    }
    const float pqv = p[10] * inv;
    __builtin_amdgcn_sched_barrier(0);

    // ---- Phase E+F fused, 4-channel chunks: y[4] -> fold into o[8] ----
    float o[8];
#pragma unroll
    for (int d = 0; d < 8; ++d)
        o[d] = fmaf(pqv, qp[d], Pn * b_kv[64 + h8 + d]);
#pragma unroll
    for (int cch = 0; cch < 16; ++cch) {
        float y[4];
#pragma unroll
        for (int ci = 0; ci < 4; ++ci) y[ci] = 0.f;
#pragma unroll
        for (int t = 0; t < 9; ++t) {
#pragma unroll
            for (int ci = 0; ci < 4; ++ci) {
                const int c  = cch * 4 + ci;
                const int f  = t * 64 + c;
                const int ch = f / 9;
                const int l  = f - ch * 9;
                const int wi = l / 3;
                const int wj = l - wi * 3;
                float a = xl[ch * CHS + wi * XS + wj];
                y[ci] = fmaf(pn[t], a, y[ci]);
            }
        }
#pragma unroll
        for (int ci = 0; ci < 4; ++ci) {
            const int c = cch * 4 + ci;
            const float* w = W_kv + (c << 7) + 64 + h8;
#pragma unroll
            for (int d = 0; d < 8; ++d) o[d] = fmaf(y[ci], w[d], o[d]);
        }
        __builtin_amdgcn_sched_barrier(0);
    }
#pragma unroll
    for (int d = 0; d < 8; ++d) pre_s[lane * 65 + h8 + d] = o[d];
    __syncthreads();

    // ---- Phase G: output projection; wave h -> channels h8..h8+7 ----
    const int j0 = h8;
    float o2[8];
#pragma unroll
    for (int j = 0; j < 8; ++j) o2[j] = b_proj[j0 + j];
#pragma unroll
    for (int c = 0; c < 64; ++c) {
        float a = pre_s[lane * 65 + c];
        const float* w = W_proj + (c << 6) + j0;
#pragma unroll
        for (int j = 0; j < 8; ++j) o2[j] = fmaf(a, w[j], o2[j]);
    }
    float* ob = out + (size_t)bb * (64 * 64 * 64);
    const int pr = h0 + tr, pc = w0 + tc;
#pragma unroll
    for (int j = 0; j < 8; ++j)
        ob[((j0 + j) << 12) + (pr << 6) + pc] = o2[j];
}

extern "C" void kernel_launch(void* const* d_in, const int* in_sizes, int n_in,
                              void* d_out, int out_size, void* d_ws, size_t ws_size,
                              hipStream_t stream)
{
    const float* x      = (const float*)d_in[0];
    const float* W_qk   = (const float*)d_in[1];
    const float* b_qk   = (const float*)d_in[2];
    const float* W_kv   = (const float*)d_in[3];
    const float* b_kv   = (const float*)d_in[4];
    const float* W_proj = (const float*)d_in[5];
    const float* b_proj = (const float*)d_in[6];
    float* out = (float*)d_out;

    pix_attn_main<<<512, 512, 0, stream>>>(x, W_qk, b_qk, W_kv, b_kv,
                                           W_proj, b_proj, out);
}

// Round 6
// 153.202 us; speedup vs baseline: 3.5080x; 1.0014x over previous
//
#include <hip/hip_runtime.h>
#include <math.h>

// pix_attn R5: identical to R4 except __launch_bounds__(512,1).
// Empirical VGPR cap = 256/min_waves_per_EU. At (512,2)=128 the kernel STILL
// spilled (~160 dwords/thread: WRITE exactly 160 MB) because the scheduler
// hoists weight-load results across chunks and the ~102 usable SGPRs overflow
// into VGPRs. (512,1) -> 256-VGPR cap absorbs the whole hoisted working set;
// grid (512 blocks / 256 CU) runs 2 blocks/CU back-to-back at 2 waves/SIMD,
// which zero-spill arithmetic says is ~35-70us vs 153us with the spill storm.
//  - u-trick:  lg_raw[t] = sum_c xs[t,c] * u_c,  u = W_k^h · q
//  - y-trick:  x_fusion = sum_c y_c * W_v[c,:] + (sum p')*b_v
//  - tile 4x16, stride-24 LDS (exact 2-way banks = free), 64B coalesced stores
//  - wave = head -> all weight reads are wave-uniform scalar loads
//
// Scramble: f = t*64 + c  <->  ch = f/9, l = f%9, (wi,wj) = (l/3, l%3)

#define XS  24      // padded row stride (floats)
#define CHS 144     // per-channel tile stride = 6 rows * 24

__global__ __launch_bounds__(512, 1) void pix_attn_main(
    const float* __restrict__ x,
    const float* __restrict__ W_qk,
    const float* __restrict__ b_qk,
    const float* __restrict__ W_kv,
    const float* __restrict__ b_kv,
    const float* __restrict__ W_proj,
    const float* __restrict__ b_proj,
    float* __restrict__ out)
{
    __shared__ float xt[64 * CHS];     // 36864 B : [ch][6 rows][24]
    __shared__ float pre_s[64 * 65];   // 16640 B : [pixel][65]

    const int tid  = threadIdx.x;
    const int blk  = blockIdx.x;
    const int bb   = blk >> 6;               // image
    const int t_id = blk & 63;               // 16 row-tiles x 4 col-tiles
    const int h0   = (t_id >> 2) << 2;       // tile row origin (step 4)
    const int w0   = (t_id & 3) << 4;        // tile col origin (step 16)

    // ---- stage x tile (6 rows x 18 cols halo per channel, reflect pad) ----
    const float* xb = x + (size_t)bb * (64 * 64 * 64);
    for (int idx = tid; idx < 64 * 6 * 18; idx += 512) {
        int ch  = idx / 108;
        int rem = idx - ch * 108;
        int r   = rem / 18;
        int cc  = rem - r * 18;
        int gr  = h0 + r - 1;
        gr = (gr < 0) ? 1 : ((gr > 63) ? 62 : gr);
        int gc  = w0 + cc - 1;
        gc = (gc < 0) ? 1 : ((gc > 63) ? 62 : gc);
        xt[ch * CHS + r * XS + cc] = xb[(ch << 12) + (gr << 6) + gc];
    }
    __syncthreads();

    const int h    = __builtin_amdgcn_readfirstlane(tid >> 6);  // wave = head
    const int h8   = h << 3;
    const int lane = tid & 63;
    const int tr   = lane >> 4;      // 0..3
    const int tc   = lane & 15;      // 0..15
    const float* xl = xt + tr * XS + tc;       // lane base, reads at +imm
    const float scale = 0.35355339059327373f;  // 8^-0.5

    // ---- Phase A: q / q_ projection (center pixel = +XS+1) ----
    float q[8], qp[8];
#pragma unroll
    for (int d = 0; d < 8; ++d) {
        q[d]  = b_qk[h8 + d];
        qp[d] = b_qk[64 + h8 + d];
    }
#pragma unroll
    for (int cc2 = 0; cc2 < 2; ++cc2) {
#pragma unroll
        for (int ci = 0; ci < 32; ++ci) {
            const int c = cc2 * 32 + ci;
            float a = xl[c * CHS + XS + 1];
            const float* w = W_qk + (c << 7) + h8;
#pragma unroll
            for (int d = 0; d < 8; ++d) {
                q[d]  = fmaf(a, w[d], q[d]);
                qp[d] = fmaf(a, w[64 + d], qp[d]);
            }
        }
        __builtin_amdgcn_sched_barrier(0);
    }
    float qv = 0.f;
#pragma unroll
    for (int d = 0; d < 8; ++d) qv = fmaf(q[d], qp[d], qv);
    float beta = 0.f;
#pragma unroll
    for (int d = 0; d < 8; ++d) beta = fmaf(q[d], b_kv[h8 + d], beta);
    __builtin_amdgcn_sched_barrier(0);

    // ---- Phase B+C fused, 4-channel chunks: u[4] -> logit scan (36 reads) ----
    float lgA[9], lgB[9];
#pragma unroll
    for (int t = 0; t < 9; ++t) { lgA[t] = 0.f; lgB[t] = 0.f; }
#pragma unroll
    for (int cch = 0; cch < 16; ++cch) {
        float u[4];
#pragma unroll
        for (int ci = 0; ci < 4; ++ci) {
            const int c = cch * 4 + ci;
            const float* w = W_kv + (c << 7) + h8;
            float s = q[0] * w[0];
#pragma unroll
            for (int d = 1; d < 8; ++d) s = fmaf(q[d], w[d], s);
            u[ci] = s;
        }
#pragma unroll
        for (int t = 0; t < 9; ++t) {
#pragma unroll
            for (int ci = 0; ci < 4; ++ci) {
                const int c  = cch * 4 + ci;
                const int f  = t * 64 + c;
                const int ch = f / 9;
                const int l  = f - ch * 9;
                const int wi = l / 3;
                const int wj = l - wi * 3;
                float a = xl[ch * CHS + wi * XS + wj];
                if (c & 1) lgB[t] = fmaf(a, u[ci], lgB[t]);
                else       lgA[t] = fmaf(a, u[ci], lgA[t]);
            }
        }
        __builtin_amdgcn_sched_barrier(0);
    }

    // ---- Phase D: softmax over {9 tokens, global, qv} ----
    float lg[11];
    float lgsum = 0.f;
#pragma unroll
    for (int t = 0; t < 9; ++t) {
        float r = lgA[t] + lgB[t];
        lgsum += r;
        lg[t] = (r + beta) * scale;
    }
    lg[9]  = (lgsum * (1.f / 9.f) + beta) * scale;
    lg[10] = qv;
    float m = lg[0];
#pragma unroll
    for (int i = 1; i < 11; ++i) m = fmaxf(m, lg[i]);
    float p[11], denom = 0.f;
#pragma unroll
    for (int i = 0; i < 11; ++i) { p[i] = __expf(lg[i] - m); denom += p[i]; }
    float inv = 1.f / denom;
    float pn[9], Pn = 0.f;
#pragma unroll
    for (int t = 0; t < 9; ++t) {
        pn[t] = (p[t] + p[9] * (1.f / 9.f)) * inv;
        Pn += pn[t];
    }
    const float pqv = p[10] * inv;
    __builtin_amdgcn_sched_barrier(0);

    // ---- Phase E+F fused, 4-channel chunks: y[4] -> fold into o[8] ----
    float o[8];
#pragma unroll
    for (int d = 0; d < 8; ++d)
        o[d] = fmaf(pqv, qp[d], Pn * b_kv[64 + h8 + d]);
#pragma unroll
    for (int cch = 0; cch < 16; ++cch) {
        float y[4];
#pragma unroll
        for (int ci = 0; ci < 4; ++ci) y[ci] = 0.f;
#pragma unroll
        for (int t = 0; t < 9; ++t) {
#pragma unroll
            for (int ci = 0; ci < 4; ++ci) {
                const int c  = cch * 4 + ci;
                const int f  = t * 64 + c;
                const int ch = f / 9;
                const int l  = f - ch * 9;
                const int wi = l / 3;
                const int wj = l - wi * 3;
                float a = xl[ch * CHS + wi * XS + wj];
                y[ci] = fmaf(pn[t], a, y[ci]);
            }
        }
#pragma unroll
        for (int ci = 0; ci < 4; ++ci) {
            const int c = cch * 4 + ci;
            const float* w = W_kv + (c << 7) + 64 + h8;
#pragma unroll
            for (int d = 0; d < 8; ++d) o[d] = fmaf(y[ci], w[d], o[d]);
        }
        __builtin_amdgcn_sched_barrier(0);
    }
#pragma unroll
    for (int d = 0; d < 8; ++d) pre_s[lane * 65 + h8 + d] = o[d];
    __syncthreads();

    // ---- Phase G: output projection; wave h -> channels h8..h8+7 ----
    const int j0 = h8;
    float o2[8];
#pragma unroll
    for (int j = 0; j < 8; ++j) o2[j] = b_proj[j0 + j];
#pragma unroll
    for (int c = 0; c < 64; ++c) {
        float a = pre_s[lane * 65 + c];
        const float* w = W_proj + (c << 6) + j0;
#pragma unroll
        for (int j = 0; j < 8; ++j) o2[j] = fmaf(a, w[j], o2[j]);
    }
    float* ob = out + (size_t)bb * (64 * 64 * 64);
    const int pr = h0 + tr, pc = w0 + tc;
#pragma unroll
    for (int j = 0; j < 8; ++j)
        ob[((j0 + j) << 12) + (pr << 6) + pc] = o2[j];
}

extern "C" void kernel_launch(void* const* d_in, const int* in_sizes, int n_in,
                              void* d_out, int out_size, void* d_ws, size_t ws_size,
                              hipStream_t stream)
{
    const float* x      = (const float*)d_in[0];
    const float* W_qk   = (const float*)d_in[1];
    const float* b_qk   = (const float*)d_in[2];
    const float* W_kv   = (const float*)d_in[3];
    const float* b_kv   = (const float*)d_in[4];
    const float* W_proj = (const float*)d_in[5];
    const float* b_proj = (const float*)d_in[6];
    float* out = (float*)d_out;

    pix_attn_main<<<512, 512, 0, stream>>>(x, W_qk, b_qk, W_kv, b_kv,
                                           W_proj, b_proj, out);
}

// Round 7
// 92.585 us; speedup vs baseline: 5.8047x; 1.6547x over previous
//
#include <hip/hip_runtime.h>
#include <math.h>

// pix_attn R6: 256-thread blocks (4 waves = 1 wave/SIMD) -> VGPR cap 256.
// (512,N) blocks geometrically force >=2 waves/SIMD -> cap 128 -> the
// allocator's live-range splitting spilled ~160 dwords/thread (R4/R5).
//  - wave owns 2 adjacent heads; scan reads SHARED between heads (halves
//    per-CU scan LDS instructions vs wave-per-head)
//  - laundered per-(t,chunk) bases keep ds offsets <=8-bit so the DS combiner
//    can pair reads into ds_read2_b32
//  - pre_s aliased into xt's LDS (36.9 KB total), barrier-separated
//  - u-trick:  lg_raw[t] = sum_c xs[t,c] * u_c,  u = W_k^h · q
//  - y-trick:  x_fusion = sum_c y_c * W_v[c,:] + (sum p')*b_v
//  - tile 4x16, stride-24 LDS (exact 2-way banks = free), 64B coalesced stores
//
// Scramble: f = t*64 + c  <->  ch = f/9, l = f%9, (wi,wj) = (l/3, l%3)

#define XS  24      // padded row stride (floats)
#define CHS 144     // per-channel tile stride = 6 rows * 24
#define LAUNDER(v) asm volatile("" : "+v"(v))

__global__ __launch_bounds__(256, 1) void pix_attn_main(
    const float* __restrict__ x,
    const float* __restrict__ W_qk,
    const float* __restrict__ b_qk,
    const float* __restrict__ W_kv,
    const float* __restrict__ b_kv,
    const float* __restrict__ W_proj,
    const float* __restrict__ b_proj,
    float* __restrict__ out)
{
    __shared__ float smem[64 * CHS];   // 36864 B: xt during scans, pre_s after

    const int tid  = threadIdx.x;
    const int blk  = blockIdx.x;
    const int bb   = blk >> 6;               // image
    const int t_id = blk & 63;               // 16 row-tiles x 4 col-tiles
    const int h0r  = (t_id >> 2) << 2;       // tile row origin (step 4)
    const int w0c  = (t_id & 3) << 4;        // tile col origin (step 16)

    // ---- stage x tile (6 rows x 18 cols halo per channel, reflect pad) ----
    const float* xb = x + (size_t)bb * (64 * 64 * 64);
    for (int idx = tid; idx < 64 * 6 * 18; idx += 256) {
        int ch  = idx / 108;
        int rem = idx - ch * 108;
        int r   = rem / 18;
        int cc  = rem - r * 18;
        int gr  = h0r + r - 1;
        gr = (gr < 0) ? 1 : ((gr > 63) ? 62 : gr);
        int gc  = w0c + cc - 1;
        gc = (gc < 0) ? 1 : ((gc > 63) ? 62 : gc);
        smem[ch * CHS + r * XS + cc] = xb[(ch << 12) + (gr << 6) + gc];
    }
    __syncthreads();

    const int wv   = __builtin_amdgcn_readfirstlane(tid >> 6);  // 0..3
    const int hA8  = wv << 4;        // head A = 2wv (cols hA8..), head B = +8
    const int lane = tid & 63;
    const int tr   = lane >> 4;      // 0..3
    const int tc   = lane & 15;      // 0..15
    const float* xl = smem + tr * XS + tc;
    const float scale = 0.35355339059327373f;  // 8^-0.5

    // ---- Phase A: q/q_ for both heads (paired center reads) ----
    float qA[8], qpA[8], qB[8], qpB[8];
#pragma unroll
    for (int d = 0; d < 8; ++d) {
        qA[d]  = b_qk[hA8 + d];       qB[d]  = b_qk[hA8 + 8 + d];
        qpA[d] = b_qk[64 + hA8 + d];  qpB[d] = b_qk[64 + hA8 + 8 + d];
    }
#pragma unroll
    for (int cp = 0; cp < 32; ++cp) {
        int cb = (cp * 2) * CHS; LAUNDER(cb);
        const float* x2 = xl + cb;
        float a0 = x2[XS + 1];
        float a1 = x2[CHS + XS + 1];
        const float* w0 = W_qk + ((cp * 2) << 7) + hA8;
        const float* w1 = W_qk + ((cp * 2 + 1) << 7) + hA8;
#pragma unroll
        for (int d = 0; d < 8; ++d) {
            qA[d]  = fmaf(a0, w0[d],      qA[d]);
            qB[d]  = fmaf(a0, w0[8 + d],  qB[d]);
            qpA[d] = fmaf(a0, w0[64 + d], qpA[d]);
            qpB[d] = fmaf(a0, w0[72 + d], qpB[d]);
            qA[d]  = fmaf(a1, w1[d],      qA[d]);
            qB[d]  = fmaf(a1, w1[8 + d],  qB[d]);
            qpA[d] = fmaf(a1, w1[64 + d], qpA[d]);
            qpB[d] = fmaf(a1, w1[72 + d], qpB[d]);
        }
        if ((cp & 7) == 7) __builtin_amdgcn_sched_barrier(0);
    }
    float qvA = 0.f, qvB = 0.f, betaA = 0.f, betaB = 0.f;
#pragma unroll
    for (int d = 0; d < 8; ++d) {
        qvA = fmaf(qA[d], qpA[d], qvA);
        qvB = fmaf(qB[d], qpB[d], qvB);
        betaA = fmaf(qA[d], b_kv[hA8 + d], betaA);
        betaB = fmaf(qB[d], b_kv[hA8 + 8 + d], betaB);
    }
    __builtin_amdgcn_sched_barrier(0);

    // ---- Scan 1: logits for both heads, shared reads, paired ds_read2 ----
    float lga[9], lgb[9];
#pragma unroll
    for (int t = 0; t < 9; ++t) { lga[t] = 0.f; lgb[t] = 0.f; }
#pragma unroll
    for (int cch = 0; cch < 16; ++cch) {
        float uA[4], uB[4];
#pragma unroll
        for (int ci = 0; ci < 4; ++ci) {
            const int c = cch * 4 + ci;
            const float* w = W_kv + (c << 7) + hA8;
            float sA = qA[0] * w[0], sB = qB[0] * w[8];
#pragma unroll
            for (int d = 1; d < 8; ++d) {
                sA = fmaf(qA[d], w[d], sA);
                sB = fmaf(qB[d], w[8 + d], sB);
            }
            uA[ci] = sA; uB[ci] = sB;
        }
#pragma unroll
        for (int t = 0; t < 9; ++t) {
            const int f0  = t * 64 + cch * 4;
            const int ch0 = f0 / 9;
            int cb = ch0 * CHS; LAUNDER(cb);
            const float* x2 = xl + cb;
#pragma unroll
            for (int ci = 0; ci < 4; ++ci) {
                const int f  = f0 + ci;
                const int ch = f / 9;
                const int l  = f - ch * 9;
                const int wi = l / 3;
                const int wj = l - wi * 3;
                float a = x2[(ch - ch0) * CHS + wi * XS + wj];
                lga[t] = fmaf(a, uA[ci], lga[t]);
                lgb[t] = fmaf(a, uB[ci], lgb[t]);
            }
        }
        __builtin_amdgcn_sched_barrier(0);
    }

    // ---- softmax per head over {9 tokens, global, qv} ----
    float pnA[9], pnB[9], PnA = 0.f, PnB = 0.f, pqvA, pqvB;
    {
        float lgs = 0.f, l2[11];
#pragma unroll
        for (int t = 0; t < 9; ++t) { lgs += lga[t]; l2[t] = (lga[t] + betaA) * scale; }
        l2[9]  = (lgs * (1.f / 9.f) + betaA) * scale;
        l2[10] = qvA;
        float m = l2[0];
#pragma unroll
        for (int i = 1; i < 11; ++i) m = fmaxf(m, l2[i]);
        float pp[11], den = 0.f;
#pragma unroll
        for (int i = 0; i < 11; ++i) { pp[i] = __expf(l2[i] - m); den += pp[i]; }
        float inv = 1.f / den;
#pragma unroll
        for (int t = 0; t < 9; ++t) { pnA[t] = (pp[t] + pp[9] * (1.f / 9.f)) * inv; PnA += pnA[t]; }
        pqvA = pp[10] * inv;
    }
    {
        float lgs = 0.f, l2[11];
#pragma unroll
        for (int t = 0; t < 9; ++t) { lgs += lgb[t]; l2[t] = (lgb[t] + betaB) * scale; }
        l2[9]  = (lgs * (1.f / 9.f) + betaB) * scale;
        l2[10] = qvB;
        float m = l2[0];
#pragma unroll
        for (int i = 1; i < 11; ++i) m = fmaxf(m, l2[i]);
        float pp[11], den = 0.f;
#pragma unroll
        for (int i = 0; i < 11; ++i) { pp[i] = __expf(l2[i] - m); den += pp[i]; }
        float inv = 1.f / den;
#pragma unroll
        for (int t = 0; t < 9; ++t) { pnB[t] = (pp[t] + pp[9] * (1.f / 9.f)) * inv; PnB += pnB[t]; }
        pqvB = pp[10] * inv;
    }
    __builtin_amdgcn_sched_barrier(0);

    // ---- Scan 2: y for both heads (shared reads) folded into o ----
    float oA[8], oB[8];
#pragma unroll
    for (int d = 0; d < 8; ++d) {
        oA[d] = fmaf(pqvA, qpA[d], PnA * b_kv[64 + hA8 + d]);
        oB[d] = fmaf(pqvB, qpB[d], PnB * b_kv[64 + hA8 + 8 + d]);
    }
#pragma unroll
    for (int cch = 0; cch < 16; ++cch) {
        float yA[4], yB[4];
#pragma unroll
        for (int ci = 0; ci < 4; ++ci) { yA[ci] = 0.f; yB[ci] = 0.f; }
#pragma unroll
        for (int t = 0; t < 9; ++t) {
            const int f0  = t * 64 + cch * 4;
            const int ch0 = f0 / 9;
            int cb = ch0 * CHS; LAUNDER(cb);
            const float* x2 = xl + cb;
#pragma unroll
            for (int ci = 0; ci < 4; ++ci) {
                const int f  = f0 + ci;
                const int ch = f / 9;
                const int l  = f - ch * 9;
                const int wi = l / 3;
                const int wj = l - wi * 3;
                float a = x2[(ch - ch0) * CHS + wi * XS + wj];
                yA[ci] = fmaf(pnA[t], a, yA[ci]);
                yB[ci] = fmaf(pnB[t], a, yB[ci]);
            }
        }
#pragma unroll
        for (int ci = 0; ci < 4; ++ci) {
            const int c = cch * 4 + ci;
            const float* w = W_kv + (c << 7) + 64 + hA8;
#pragma unroll
            for (int d = 0; d < 8; ++d) {
                oA[d] = fmaf(yA[ci], w[d], oA[d]);
                oB[d] = fmaf(yB[ci], w[8 + d], oB[d]);
            }
        }
        __builtin_amdgcn_sched_barrier(0);
    }

    // ---- hand off through pre_s (aliased into smem) ----
    __syncthreads();                       // all xt reads complete
    float* pre_s = smem;                   // [pixel][65]
#pragma unroll
    for (int d = 0; d < 8; ++d) {
        pre_s[lane * 65 + hA8 + d]     = oA[d];
        pre_s[lane * 65 + hA8 + 8 + d] = oB[d];
    }
    __syncthreads();

    // ---- Phase G: output projection; wave wv -> channels wv*16.. ----
    const int j0 = wv << 4;
    float o2[16];
#pragma unroll
    for (int j = 0; j < 16; ++j) o2[j] = b_proj[j0 + j];
#pragma unroll
    for (int c = 0; c < 64; ++c) {
        float a = pre_s[lane * 65 + c];
        const float* w = W_proj + (c << 6) + j0;
#pragma unroll
        for (int j = 0; j < 16; ++j) o2[j] = fmaf(a, w[j], o2[j]);
    }
    float* ob = out + (size_t)bb * (64 * 64 * 64);
    const int pr = h0r + tr, pc = w0c + tc;
#pragma unroll
    for (int j = 0; j < 16; ++j)
        ob[((j0 + j) << 12) + (pr << 6) + pc] = o2[j];
}

extern "C" void kernel_launch(void* const* d_in, const int* in_sizes, int n_in,
                              void* d_out, int out_size, void* d_ws, size_t ws_size,
                              hipStream_t stream)
{
    const float* x      = (const float*)d_in[0];
    const float* W_qk   = (const float*)d_in[1];
    const float* b_qk   = (const float*)d_in[2];
    const float* W_kv   = (const float*)d_in[3];
    const float* b_kv   = (const float*)d_in[4];
    const float* W_proj = (const float*)d_in[5];
    const float* b_proj = (const float*)d_in[6];
    float* out = (float*)d_out;

    pix_attn_main<<<512, 256, 0, stream>>>(x, W_qk, b_qk, W_kv, b_kv,
                                           W_proj, b_proj, out);
}

// Round 8
// 86.294 us; speedup vs baseline: 6.2279x; 1.0729x over previous
//
#include <hip/hip_runtime.h>
#include <math.h>

// pix_attn R7: occupancy 2x via tile-split + atomic merge; by-ch scans.
//  - R6 result: no spill at 256-thr blocks (VGPR 84), but grid 512 = 2 blk/CU
//    = 8 waves/CU -> latency-bound (VALUBusy 22%, pipes ~25us, wall 92us).
//  - Now: 2 blocks per tile (4 heads each), grid 1024 = 4 blk/CU = 16 waves.
//    Output proj is partial (32 pre-channels) merged by unsafeAtomicAdd into
//    memset-zeroed d_out: 2 commutative adds/element -> deterministic.
//  - Scans by channel-pair: 18 window values per laundered base at small
//    compile-time offsets -> DS-combiner pairs into ds_read2_b32.
//  - Block-pair dispatch swizzle keeps both halves of a tile on one XCD.
//  - u-trick:  lg_raw[t] = sum_c xs[t,c]*u[c],  u = W_k^h . q
//  - y-trick:  o = sum_c y[c]*W_v[c,:] + (sum p')*b_v + pqv*q_
//
// Scramble: f = t*64 + c <-> ch = f/9, l = f%9, (wi,wj) = (l/3, l%3);
// equivalently for ch fixed: f = 9ch+l, t = f>>6, c = f&63.

#define XS  24      // padded row stride (floats)
#define CHS 144     // per-channel tile stride = 6 rows * 24
#define LAUNDER(v) asm volatile("" : "+v"(v))

__global__ __launch_bounds__(256, 1) void pix_attn_main(
    const float* __restrict__ x,
    const float* __restrict__ W_qk,
    const float* __restrict__ b_qk,
    const float* __restrict__ W_kv,
    const float* __restrict__ b_kv,
    const float* __restrict__ W_proj,
    const float* __restrict__ b_proj,
    float* __restrict__ out)
{
    __shared__ float smem[64 * CHS];   // 36864 B: xt during scans, pre after

    const int tid = threadIdx.x;
    // dispatch swizzle: ids j and j+8 are the two head-groups of one tile
    // -> same XCD (j%8), adjacent in time (L2 reuse of the staged tile).
    const int j   = blockIdx.x;
    const int g   = j >> 4;
    const int tile = g * 8 + (j & 7);
    const int hg   = (j >> 3) & 1;           // head group 0..1
    const int bb   = tile >> 6;              // image
    const int t_id = tile & 63;
    const int h0r  = (t_id >> 2) << 2;       // tile row origin (step 4)
    const int w0c  = (t_id & 3) << 4;        // tile col origin (step 16)

    // ---- stage x tile (6 rows x 18 cols halo per channel, reflect pad) ----
    const float* xb = x + (size_t)bb * (64 * 64 * 64);
    for (int it = 0; it < 27; ++it) {
        int idx = it * 256 + tid;            // 6912 = 27*256 exact
        int ch  = idx / 108;
        int rem = idx - ch * 108;
        int r   = rem / 18;
        int cc  = rem - r * 18;
        int gr  = h0r + r - 1;
        gr = (gr < 0) ? 1 : ((gr > 63) ? 62 : gr);
        int gc  = w0c + cc - 1;
        gc = (gc < 0) ? 1 : ((gc > 63) ? 62 : gc);
        smem[ch * CHS + r * XS + cc] = xb[(ch << 12) + (gr << 6) + gc];
    }
    __syncthreads();

    const int wv   = __builtin_amdgcn_readfirstlane(tid >> 6);  // 0..3
    const int h8   = (hg * 4 + wv) << 3;     // this wave's head, col base
    const int lane = tid & 63;
    const int tr   = lane >> 4;
    const int tc   = lane & 15;
    const float* xl = smem + tr * XS + tc;
    const float scale = 0.35355339059327373f;  // 8^-0.5

    // ---- Phase A: q / q_ (center reads paired per 2 channels) ----
    float q[8], qp[8];
#pragma unroll
    for (int d = 0; d < 8; ++d) {
        q[d]  = b_qk[h8 + d];
        qp[d] = b_qk[64 + h8 + d];
    }
#pragma unroll
    for (int cp = 0; cp < 32; ++cp) {
        int cb = cp * (2 * CHS); LAUNDER(cb);
        const float* x2 = xl + cb;
        float a0 = x2[XS + 1];
        float a1 = x2[CHS + XS + 1];
        const float* w0 = W_qk + ((cp * 2) << 7) + h8;
        const float* w1 = w0 + 128;
#pragma unroll
        for (int d = 0; d < 8; ++d) {
            q[d]  = fmaf(a0, w0[d],      q[d]);
            qp[d] = fmaf(a0, w0[64 + d], qp[d]);
            q[d]  = fmaf(a1, w1[d],      q[d]);
            qp[d] = fmaf(a1, w1[64 + d], qp[d]);
        }
        if ((cp & 7) == 7) __builtin_amdgcn_sched_barrier(0);
    }
    float qv = 0.f, beta = 0.f;
#pragma unroll
    for (int d = 0; d < 8; ++d) {
        qv   = fmaf(q[d], qp[d], qv);
        beta = fmaf(q[d], b_kv[h8 + d], beta);
    }
    __builtin_amdgcn_sched_barrier(0);

    // ---- u = W_k^h . q (all 64; by-ch scan touches every c) ----
    float u[64];
#pragma unroll
    for (int c = 0; c < 64; ++c) {
        const float* w = W_kv + (c << 7) + h8;
        float s = q[0] * w[0];
#pragma unroll
        for (int d = 1; d < 8; ++d) s = fmaf(q[d], w[d], s);
        u[c] = s;
        if ((c & 15) == 15) __builtin_amdgcn_sched_barrier(0);
    }
    __builtin_amdgcn_sched_barrier(0);

    // ---- Scan 1 (by channel pair): lg[t] += xs * u ----
    float lgE[9], lgO[9];
#pragma unroll
    for (int t = 0; t < 9; ++t) { lgE[t] = 0.f; lgO[t] = 0.f; }
#pragma unroll
    for (int chp = 0; chp < 32; ++chp) {
        int cb = chp * (2 * CHS); LAUNDER(cb);
        const float* x2 = xl + cb;
#pragma unroll
        for (int s = 0; s < 2; ++s) {
#pragma unroll
            for (int l = 0; l < 9; ++l) {
                const int ch = chp * 2 + s;
                const int f  = ch * 9 + l;
                const int t  = f >> 6;
                const int c  = f & 63;
                const int wi = l / 3;
                const int wj = l - wi * 3;
                float a = x2[s * CHS + wi * XS + wj];
                if (l & 1) lgO[t] = fmaf(a, u[c], lgO[t]);
                else       lgE[t] = fmaf(a, u[c], lgE[t]);
            }
        }
        if (chp & 1) __builtin_amdgcn_sched_barrier(0);
    }

    // ---- softmax over {9 tokens, global, qv} ----
    float pn[9], Pn = 0.f, pqv;
    {
        float lgs = 0.f, l2[11];
#pragma unroll
        for (int t = 0; t < 9; ++t) {
            float r = lgE[t] + lgO[t];
            lgs += r;
            l2[t] = (r + beta) * scale;
        }
        l2[9]  = (lgs * (1.f / 9.f) + beta) * scale;
        l2[10] = qv;
        float m = l2[0];
#pragma unroll
        for (int i = 1; i < 11; ++i) m = fmaxf(m, l2[i]);
        float pp[11], den = 0.f;
#pragma unroll
        for (int i = 0; i < 11; ++i) { pp[i] = __expf(l2[i] - m); den += pp[i]; }
        float inv = 1.f / den;
#pragma unroll
        for (int t = 0; t < 9; ++t) {
            pn[t] = (pp[t] + pp[9] * (1.f / 9.f)) * inv;
            Pn += pn[t];
        }
        pqv = pp[10] * inv;
    }
    __builtin_amdgcn_sched_barrier(0);

    // ---- Scan 2 (by channel pair): y[c] += pn[t] * xs ----
    float y[64];
#pragma unroll
    for (int c = 0; c < 64; ++c) y[c] = 0.f;
#pragma unroll
    for (int chp = 0; chp < 32; ++chp) {
        int cb = chp * (2 * CHS); LAUNDER(cb);
        const float* x2 = xl + cb;
#pragma unroll
        for (int s = 0; s < 2; ++s) {
#pragma unroll
            for (int l = 0; l < 9; ++l) {
                const int ch = chp * 2 + s;
                const int f  = ch * 9 + l;
                const int t  = f >> 6;
                const int c  = f & 63;
                const int wi = l / 3;
                const int wj = l - wi * 3;
                float a = x2[s * CHS + wi * XS + wj];
                y[c] = fmaf(pn[t], a, y[c]);
            }
        }
        if (chp & 1) __builtin_amdgcn_sched_barrier(0);
    }
    __builtin_amdgcn_sched_barrier(0);

    // ---- fold: o = W_v^T y + Pn*b_v + pqv*q_ ----
    float oA[8], oB[8];
#pragma unroll
    for (int d = 0; d < 8; ++d) {
        oA[d] = fmaf(pqv, qp[d], Pn * b_kv[64 + h8 + d]);
        oB[d] = 0.f;
    }
#pragma unroll
    for (int c = 0; c < 64; ++c) {
        const float* w = W_kv + (c << 7) + 64 + h8;
#pragma unroll
        for (int d = 0; d < 8; ++d) {
            if (c & 1) oB[d] = fmaf(y[c], w[d], oB[d]);
            else       oA[d] = fmaf(y[c], w[d], oA[d]);
        }
        if ((c & 15) == 15) __builtin_amdgcn_sched_barrier(0);
    }

    // ---- handoff through pre (aliased into smem), stride 33 ----
    __syncthreads();                        // all xt reads complete
    float* pre = smem;                      // [pixel][33]
#pragma unroll
    for (int d = 0; d < 8; ++d)
        pre[lane * 33 + (wv << 3) + d] = oA[d] + oB[d];
    __syncthreads();

    // ---- partial output projection over this block's 32 pre-channels ----
    const int j0 = wv << 4;
    float o2[16];
#pragma unroll
    for (int jj = 0; jj < 16; ++jj)
        o2[jj] = (hg == 0) ? b_proj[j0 + jj] : 0.f;
    int pb = lane * 33; LAUNDER(pb);
    const float* pl = pre + pb;
#pragma unroll
    for (int c = 0; c < 32; ++c) {
        float a = pl[c];
        const float* w = W_proj + ((hg * 32 + c) << 6) + j0;
#pragma unroll
        for (int jj = 0; jj < 16; ++jj) o2[jj] = fmaf(a, w[jj], o2[jj]);
        if ((c & 15) == 15) __builtin_amdgcn_sched_barrier(0);
    }
    float* ob = out + (size_t)bb * (64 * 64 * 64);
    const int pr = h0r + tr, pc = w0c + tc;
#pragma unroll
    for (int jj = 0; jj < 16; ++jj)
        unsafeAtomicAdd(&ob[((j0 + jj) << 12) + (pr << 6) + pc], o2[jj]);
}

extern "C" void kernel_launch(void* const* d_in, const int* in_sizes, int n_in,
                              void* d_out, int out_size, void* d_ws, size_t ws_size,
                              hipStream_t stream)
{
    const float* x      = (const float*)d_in[0];
    const float* W_qk   = (const float*)d_in[1];
    const float* b_qk   = (const float*)d_in[2];
    const float* W_kv   = (const float*)d_in[3];
    const float* b_kv   = (const float*)d_in[4];
    const float* W_proj = (const float*)d_in[5];
    const float* b_proj = (const float*)d_in[6];
    float* out = (float*)d_out;

    hipMemsetAsync(out, 0, (size_t)out_size * sizeof(float), stream);
    pix_attn_main<<<1024, 256, 0, stream>>>(x, W_qk, b_qk, W_kv, b_kv,
                                            W_proj, b_proj, out);
}

// Round 9
// 70.093 us; speedup vs baseline: 7.6673x; 1.2311x over previous
//
#include <hip/hip_runtime.h>
#include <math.h>
#include <stdint.h>

// pix_attn R8: bf16 channel-pair packed LDS tile -> scan reads HALVED.
//  - R7 diagnosis: scans are 1 FMA per LDS read; LDS pipe (reads + 10M
//    conflict-cycles) is the wall, VALUBusy pinned ~28%. Occupancy didn't
//    scale with grid -> not wave-starved.
//  - Tile stored as dword = bf16(ch=2k) | bf16(ch=2k+1) (RTN pack at staging).
//    One ds_read serves 2 channels; unpack = shl/and. 288 reads/scan vs 576.
//    Threshold 7.3e-3 vs current 9.8e-4 -> bf16 tile error (~2e-3) fits.
//  - Scans by channel-pair: scan1 holds u[64] (y dead), scan2 holds y[64]
//    (u dead) -> peak live ~120 of 256 cap (256-thr block, 1 wave/SIMD min).
//  - Rest = R7: grid 1024 (2 blocks/tile, 4 heads each), memset + atomic
//    merge, stride-24 word layout (2-way banks = free), wave = head.
//
// Scramble: f = 9*ch + l ; t = f>>6, c = f&63, (wi,wj) = (l/3, l%3).
// Pair k: ch0=2k -> f0 = 18k+l ; ch1=2k+1 -> f1 = 18k+9+l.

#define XS  24      // padded row stride (words)
#define PCS 144     // per-pair tile stride = 6 rows * 24 words
#define LAUNDER(v) asm volatile("" : "+v"(v))
#define UNPK(w, a0, a1)                                   \
    do {                                                  \
        a0 = __uint_as_float((w) << 16);                  \
        a1 = __uint_as_float((w) & 0xffff0000u);          \
    } while (0)

__global__ __launch_bounds__(256, 1) void pix_attn_main(
    const float* __restrict__ x,
    const float* __restrict__ W_qk,
    const float* __restrict__ b_qk,
    const float* __restrict__ W_kv,
    const float* __restrict__ b_kv,
    const float* __restrict__ W_proj,
    const float* __restrict__ b_proj,
    float* __restrict__ out)
{
    __shared__ uint32_t smem[32 * PCS];  // 18432 B packed tile; pre_s after

    const int tid = threadIdx.x;
    // swizzle: ids j and j+8 are the two head-groups of one tile (same XCD)
    const int j    = blockIdx.x;
    const int g    = j >> 4;
    const int tile = g * 8 + (j & 7);
    const int hg   = (j >> 3) & 1;
    const int bb   = tile >> 6;
    const int t_id = tile & 63;
    const int h0r  = (t_id >> 2) << 2;
    const int w0c  = (t_id & 3) << 4;

    // ---- stage packed tile: dword = bf16(ch 2k) | bf16(ch 2k+1), RTN ----
    const float* xb = x + (size_t)bb * (64 * 64 * 64);
    for (int it = 0; it < 14; ++it) {
        int idx = it * 256 + tid;            // 3456 useful words
        if (idx < 3456) {
            int k   = idx / 108;
            int rem = idx - k * 108;
            int r   = rem / 18;
            int cc  = rem - r * 18;
            int gr  = h0r + r - 1;
            gr = (gr < 0) ? 1 : ((gr > 63) ? 62 : gr);
            int gc  = w0c + cc - 1;
            gc = (gc < 0) ? 1 : ((gc > 63) ? 62 : gc);
            const float* p0 = xb + ((k * 2) << 12) + (gr << 6) + gc;
            uint32_t b0 = __float_as_uint(p0[0]);
            uint32_t b1 = __float_as_uint(p0[4096]);
            uint32_t lo = (b0 + 0x7fffu + ((b0 >> 16) & 1u)) >> 16;
            uint32_t hi = (b1 + 0x7fffu + ((b1 >> 16) & 1u)) & 0xffff0000u;
            smem[k * PCS + r * XS + cc] = lo | hi;
        }
    }
    __syncthreads();

    const int wv   = __builtin_amdgcn_readfirstlane(tid >> 6);  // 0..3
    const int h8   = (hg * 4 + wv) << 3;     // this wave's head col base
    const int lane = tid & 63;
    const int tr   = lane >> 4;
    const int tc   = lane & 15;
    const uint32_t* xl = smem + tr * XS + tc;
    const float scale = 0.35355339059327373f;  // 8^-0.5

    // ---- Phase A: q / q_ (one packed center read per channel pair) ----
    float q[8], qp[8];
#pragma unroll
    for (int d = 0; d < 8; ++d) {
        q[d]  = b_qk[h8 + d];
        qp[d] = b_qk[64 + h8 + d];
    }
#pragma unroll
    for (int k = 0; k < 32; ++k) {
        uint32_t w = xl[k * PCS + XS + 1];
        float a0, a1; UNPK(w, a0, a1);
        const float* w0 = W_qk + ((k * 2) << 7) + h8;
        const float* w1 = w0 + 128;
#pragma unroll
        for (int d = 0; d < 8; ++d) {
            q[d]  = fmaf(a0, w0[d],      q[d]);
            qp[d] = fmaf(a0, w0[64 + d], qp[d]);
            q[d]  = fmaf(a1, w1[d],      q[d]);
            qp[d] = fmaf(a1, w1[64 + d], qp[d]);
        }
        if ((k & 7) == 7) __builtin_amdgcn_sched_barrier(0);
    }
    float qv = 0.f, beta = 0.f;
#pragma unroll
    for (int d = 0; d < 8; ++d) {
        qv   = fmaf(q[d], qp[d], qv);
        beta = fmaf(q[d], b_kv[h8 + d], beta);
    }
    __builtin_amdgcn_sched_barrier(0);

    // ---- u = W_k^h . q ----
    float u[64];
#pragma unroll
    for (int c = 0; c < 64; ++c) {
        const float* w = W_kv + (c << 7) + h8;
        float s = q[0] * w[0];
#pragma unroll
        for (int d = 1; d < 8; ++d) s = fmaf(q[d], w[d], s);
        u[c] = s;
        if ((c & 15) == 15) __builtin_amdgcn_sched_barrier(0);
    }
    __builtin_amdgcn_sched_barrier(0);

    // ---- Scan 1 (by pair): lg[t] += a * u[c], 9 packed reads per pair ----
    float lgE[9], lgO[9];
#pragma unroll
    for (int t = 0; t < 9; ++t) { lgE[t] = 0.f; lgO[t] = 0.f; }
#pragma unroll
    for (int k = 0; k < 32; ++k) {
        int cb = k * PCS; LAUNDER(cb);
        const uint32_t* x2 = xl + cb;
#pragma unroll
        for (int l = 0; l < 9; ++l) {
            const int wi = l / 3;
            const int wj = l - wi * 3;
            uint32_t w = x2[wi * XS + wj];
            float a0, a1; UNPK(w, a0, a1);
            const int f0 = 18 * k + l, f1 = f0 + 9;
            const int t0 = f0 >> 6, c0 = f0 & 63;
            const int t1 = f1 >> 6, c1 = f1 & 63;
            if (f0 & 1) lgO[t0] = fmaf(a0, u[c0], lgO[t0]);
            else        lgE[t0] = fmaf(a0, u[c0], lgE[t0]);
            if (f1 & 1) lgO[t1] = fmaf(a1, u[c1], lgO[t1]);
            else        lgE[t1] = fmaf(a1, u[c1], lgE[t1]);
        }
        if (k & 1) __builtin_amdgcn_sched_barrier(0);
    }

    // ---- softmax over {9 tokens, global, qv} ----
    float pn[9], Pn = 0.f, pqv;
    {
        float lgs = 0.f, l2[11];
#pragma unroll
        for (int t = 0; t < 9; ++t) {
            float r = lgE[t] + lgO[t];
            lgs += r;
            l2[t] = (r + beta) * scale;
        }
        l2[9]  = (lgs * (1.f / 9.f) + beta) * scale;
        l2[10] = qv;
        float m = l2[0];
#pragma unroll
        for (int i = 1; i < 11; ++i) m = fmaxf(m, l2[i]);
        float pp[11], den = 0.f;
#pragma unroll
        for (int i = 0; i < 11; ++i) { pp[i] = __expf(l2[i] - m); den += pp[i]; }
        float inv = 1.f / den;
#pragma unroll
        for (int t = 0; t < 9; ++t) {
            pn[t] = (pp[t] + pp[9] * (1.f / 9.f)) * inv;
            Pn += pn[t];
        }
        pqv = pp[10] * inv;
    }
    __builtin_amdgcn_sched_barrier(0);

    // ---- Scan 2 (by pair): y[c] += pn[t] * a ----
    float y[64];
#pragma unroll
    for (int c = 0; c < 64; ++c) y[c] = 0.f;
#pragma unroll
    for (int k = 0; k < 32; ++k) {
        int cb = k * PCS; LAUNDER(cb);
        const uint32_t* x2 = xl + cb;
#pragma unroll
        for (int l = 0; l < 9; ++l) {
            const int wi = l / 3;
            const int wj = l - wi * 3;
            uint32_t w = x2[wi * XS + wj];
            float a0, a1; UNPK(w, a0, a1);
            const int f0 = 18 * k + l, f1 = f0 + 9;
            const int t0 = f0 >> 6, c0 = f0 & 63;
            const int t1 = f1 >> 6, c1 = f1 & 63;
            y[c0] = fmaf(pn[t0], a0, y[c0]);
            y[c1] = fmaf(pn[t1], a1, y[c1]);
        }
        if (k & 1) __builtin_amdgcn_sched_barrier(0);
    }
    __builtin_amdgcn_sched_barrier(0);

    // ---- fold: o = W_v^T y + Pn*b_v + pqv*q_ ----
    float oA[8], oB[8];
#pragma unroll
    for (int d = 0; d < 8; ++d) {
        oA[d] = fmaf(pqv, qp[d], Pn * b_kv[64 + h8 + d]);
        oB[d] = 0.f;
    }
#pragma unroll
    for (int c = 0; c < 64; ++c) {
        const float* w = W_kv + (c << 7) + 64 + h8;
#pragma unroll
        for (int d = 0; d < 8; ++d) {
            if (c & 1) oB[d] = fmaf(y[c], w[d], oB[d]);
            else       oA[d] = fmaf(y[c], w[d], oA[d]);
        }
        if ((c & 15) == 15) __builtin_amdgcn_sched_barrier(0);
    }

    // ---- handoff through pre (aliased into smem), stride 33 ----
    __syncthreads();                        // all packed-tile reads complete
    float* pre = (float*)smem;              // [pixel][33]
#pragma unroll
    for (int d = 0; d < 8; ++d)
        pre[lane * 33 + (wv << 3) + d] = oA[d] + oB[d];
    __syncthreads();

    // ---- partial output projection over this block's 32 pre-channels ----
    const int j0 = wv << 4;
    float o2[16];
#pragma unroll
    for (int jj = 0; jj < 16; ++jj)
        o2[jj] = (hg == 0) ? b_proj[j0 + jj] : 0.f;
    int pb = lane * 33; LAUNDER(pb);
    const float* pl = pre + pb;
#pragma unroll
    for (int c = 0; c < 32; ++c) {
        float a = pl[c];
        const float* w = W_proj + ((hg * 32 + c) << 6) + j0;
#pragma unroll
        for (int jj = 0; jj < 16; ++jj) o2[jj] = fmaf(a, w[jj], o2[jj]);
        if ((c & 15) == 15) __builtin_amdgcn_sched_barrier(0);
    }
    float* ob = out + (size_t)bb * (64 * 64 * 64);
    const int pr = h0r + tr, pc = w0c + tc;
#pragma unroll
    for (int jj = 0; jj < 16; ++jj)
        unsafeAtomicAdd(&ob[((j0 + jj) << 12) + (pr << 6) + pc], o2[jj]);
}

extern "C" void kernel_launch(void* const* d_in, const int* in_sizes, int n_in,
                              void* d_out, int out_size, void* d_ws, size_t ws_size,
                              hipStream_t stream)
{
    const float* x      = (const float*)d_in[0];
    const float* W_qk   = (const float*)d_in[1];
    const float* b_qk   = (const float*)d_in[2];
    const float* W_kv   = (const float*)d_in[3];
    const float* b_kv   = (const float*)d_in[4];
    const float* W_proj = (const float*)d_in[5];
    const float* b_proj = (const float*)d_in[6];
    float* out = (float*)d_out;

    hipMemsetAsync(out, 0, (size_t)out_size * sizeof(float), stream);
    pix_attn_main<<<1024, 256, 0, stream>>>(x, W_qk, b_qk, W_kv, b_kv,
                                            W_proj, b_proj, out);
}

// Round 10
// 68.413 us; speedup vs baseline: 7.8556x; 1.0246x over previous
//
#include <hip/hip_runtime.h>
#include <math.h>
#include <stdint.h>

// pix_attn R9: quad-group b128 scans — one ds_read_b128 = 8 channels.
//  - R8 was issue-bound: ~670 LDS instrs/wave feeding 1:1-ish FMA stream,
//    VALUBusy 31%, wall 2x max-pipe. Now tile = [g=ch/8][6r][18c][4 dwords]
//    (dword = bf16 ch 8g+2w | ch 8g+2w+1). Scan reads 288->72, Phase A 32->8.
//  - 16-lane rows read 256B contiguous (free); tr rows +288B -> banks
//    {0,8,16,24} -> <=2-way = free. Explicit b128 kills read2-merge conflicts.
//  - Register budget: single base + imm offsets; fences mid-g cap in-flight
//    at ~20 VGPR -> peak live ~116 (MUST stay <=128 or waves/SIMD halves).
//  - Rest = R8: grid 1024 (2 blocks/tile, 4 heads), memset+unsafeAtomicAdd
//    merge, u-trick / y-trick, wave = head, 256-thr blocks.
//
// Scramble: f = 9*ch + l ; t = f>>6, c = f&63, (wi,wj) = (l/3, l%3).

#define GS 432      // group stride (words) = 6 rows * 72
#define RS 72       // row stride (words) = 18 cols * 4
#define LAUNDER(v) asm volatile("" : "+v"(v))

__global__ __launch_bounds__(256, 1) void pix_attn_main(
    const float* __restrict__ x,
    const float* __restrict__ W_qk,
    const float* __restrict__ b_qk,
    const float* __restrict__ W_kv,
    const float* __restrict__ b_kv,
    const float* __restrict__ W_proj,
    const float* __restrict__ b_proj,
    float* __restrict__ out)
{
    __shared__ uint32_t smem[8 * GS];    // 13824 B packed tile; pre_s after

    const int tid = threadIdx.x;
    // swizzle: ids j and j+8 are the two head-groups of one tile (same XCD)
    const int j    = blockIdx.x;
    const int g_   = j >> 4;
    const int tile = g_ * 8 + (j & 7);
    const int hg   = (j >> 3) & 1;
    const int bb   = tile >> 6;
    const int t_id = tile & 63;
    const int h0r  = (t_id >> 2) << 2;
    const int w0c  = (t_id & 3) << 4;

    // ---- stage packed tile: word(g,r,cc,w) = bf16(ch=8g+2w)|bf16(+1) ----
    const float* xb = x + (size_t)bb * (64 * 64 * 64);
    for (int it = 0; it < 14; ++it) {
        int idx = it * 256 + tid;            // 3456 words
        if (idx < 3456) {
            int pair = idx / 108;            // 0..31
            int pix  = idx - pair * 108;
            int r    = pix / 18;
            int cc   = pix - r * 18;
            int gq   = pair >> 2;
            int w    = pair & 3;
            int gr   = h0r + r - 1;
            gr = (gr < 0) ? 1 : ((gr > 63) ? 62 : gr);
            int gc   = w0c + cc - 1;
            gc = (gc < 0) ? 1 : ((gc > 63) ? 62 : gc);
            const float* p0 = xb + ((pair * 2) << 12) + (gr << 6) + gc;
            uint32_t b0 = __float_as_uint(p0[0]);
            uint32_t b1 = __float_as_uint(p0[4096]);
            uint32_t lo = (b0 + 0x7fffu + ((b0 >> 16) & 1u)) >> 16;
            uint32_t hi = (b1 + 0x7fffu + ((b1 >> 16) & 1u)) & 0xffff0000u;
            smem[gq * GS + r * RS + cc * 4 + w] = lo | hi;
        }
    }
    __syncthreads();

    const int wv   = __builtin_amdgcn_readfirstlane(tid >> 6);  // 0..3
    const int h8   = (hg * 4 + wv) << 3;     // this wave's head col base
    const int lane = tid & 63;
    const int tr   = lane >> 4;
    const int tc   = lane & 15;
    const uint32_t* xl4 = smem + tr * RS + tc * 4;  // 16B-aligned lane base
    const float scale = 0.35355339059327373f;  // 8^-0.5

    // ---- Phase A: q / q_ (one b128 center read per 8 channels) ----
    float q[8], qp[8];
#pragma unroll
    for (int d = 0; d < 8; ++d) {
        q[d]  = b_qk[h8 + d];
        qp[d] = b_qk[64 + h8 + d];
    }
#pragma unroll
    for (int g = 0; g < 8; ++g) {
        uint4 v = *(const uint4*)(xl4 + g * GS + RS + 4);  // (+1 row, +1 col)
#pragma unroll
        for (int w = 0; w < 4; ++w) {
            uint32_t dw = (&v.x)[w];
            float a0 = __uint_as_float(dw << 16);
            float a1 = __uint_as_float(dw & 0xffff0000u);
            const float* w0 = W_qk + ((8 * g + 2 * w) << 7) + h8;
            const float* w1 = w0 + 128;
#pragma unroll
            for (int d = 0; d < 8; ++d) {
                q[d]  = fmaf(a0, w0[d],      q[d]);
                qp[d] = fmaf(a0, w0[64 + d], qp[d]);
                q[d]  = fmaf(a1, w1[d],      q[d]);
                qp[d] = fmaf(a1, w1[64 + d], qp[d]);
            }
        }
        if (g & 1) __builtin_amdgcn_sched_barrier(0);
    }
    float qv = 0.f, beta = 0.f;
#pragma unroll
    for (int d = 0; d < 8; ++d) {
        qv   = fmaf(q[d], qp[d], qv);
        beta = fmaf(q[d], b_kv[h8 + d], beta);
    }
    __builtin_amdgcn_sched_barrier(0);

    // ---- u = W_k^h . q ----
    float u[64];
#pragma unroll
    for (int c = 0; c < 64; ++c) {
        const float* w = W_kv + (c << 7) + h8;
        float s = q[0] * w[0];
#pragma unroll
        for (int d = 1; d < 8; ++d) s = fmaf(q[d], w[d], s);
        u[c] = s;
        if ((c & 15) == 15) __builtin_amdgcn_sched_barrier(0);
    }
    __builtin_amdgcn_sched_barrier(0);

    // ---- Scan 1: lg[t] += a * u[c]; 9 b128 reads per group of 8 ch ----
    float lgE[9], lgO[9];
#pragma unroll
    for (int t = 0; t < 9; ++t) { lgE[t] = 0.f; lgO[t] = 0.f; }
#pragma unroll
    for (int g = 0; g < 8; ++g) {
#pragma unroll
        for (int l = 0; l < 9; ++l) {
            const int wi = l / 3;
            const int wj = l - wi * 3;
            uint4 v = *(const uint4*)(xl4 + g * GS + wi * RS + wj * 4);
#pragma unroll
            for (int w = 0; w < 4; ++w) {
                uint32_t dw = (&v.x)[w];
                float a0 = __uint_as_float(dw << 16);
                float a1 = __uint_as_float(dw & 0xffff0000u);
                const int ch = 8 * g + 2 * w;
                const int f0 = 9 * ch + l, f1 = f0 + 9;
                const int t0 = f0 >> 6, c0 = f0 & 63;
                const int t1 = f1 >> 6, c1 = f1 & 63;
                if (f0 & 1) lgO[t0] = fmaf(a0, u[c0], lgO[t0]);
                else        lgE[t0] = fmaf(a0, u[c0], lgE[t0]);
                if (f1 & 1) lgO[t1] = fmaf(a1, u[c1], lgO[t1]);
                else        lgE[t1] = fmaf(a1, u[c1], lgE[t1]);
            }
            if (l == 3) __builtin_amdgcn_sched_barrier(0);
        }
        __builtin_amdgcn_sched_barrier(0);
    }

    // ---- softmax over {9 tokens, global, qv} ----
    float pn[9], Pn = 0.f, pqv;
    {
        float lgs = 0.f, l2[11];
#pragma unroll
        for (int t = 0; t < 9; ++t) {
            float r = lgE[t] + lgO[t];
            lgs += r;
            l2[t] = (r + beta) * scale;
        }
        l2[9]  = (lgs * (1.f / 9.f) + beta) * scale;
        l2[10] = qv;
        float m = l2[0];
#pragma unroll
        for (int i = 1; i < 11; ++i) m = fmaxf(m, l2[i]);
        float pp[11], den = 0.f;
#pragma unroll
        for (int i = 0; i < 11; ++i) { pp[i] = __expf(l2[i] - m); den += pp[i]; }
        float inv = 1.f / den;
#pragma unroll
        for (int t = 0; t < 9; ++t) {
            pn[t] = (pp[t] + pp[9] * (1.f / 9.f)) * inv;
            Pn += pn[t];
        }
        pqv = pp[10] * inv;
    }
    __builtin_amdgcn_sched_barrier(0);

    // ---- Scan 2: y[c] += pn[t] * a ----
    float y[64];
#pragma unroll
    for (int c = 0; c < 64; ++c) y[c] = 0.f;
#pragma unroll
    for (int g = 0; g < 8; ++g) {
#pragma unroll
        for (int l = 0; l < 9; ++l) {
            const int wi = l / 3;
            const int wj = l - wi * 3;
            uint4 v = *(const uint4*)(xl4 + g * GS + wi * RS + wj * 4);
#pragma unroll
            for (int w = 0; w < 4; ++w) {
                uint32_t dw = (&v.x)[w];
                float a0 = __uint_as_float(dw << 16);
                float a1 = __uint_as_float(dw & 0xffff0000u);
                const int ch = 8 * g + 2 * w;
                const int f0 = 9 * ch + l, f1 = f0 + 9;
                const int t0 = f0 >> 6, c0 = f0 & 63;
                const int t1 = f1 >> 6, c1 = f1 & 63;
                y[c0] = fmaf(pn[t0], a0, y[c0]);
                y[c1] = fmaf(pn[t1], a1, y[c1]);
            }
            if (l == 3) __builtin_amdgcn_sched_barrier(0);
        }
        __builtin_amdgcn_sched_barrier(0);
    }
    __builtin_amdgcn_sched_barrier(0);

    // ---- fold: o = W_v^T y + Pn*b_v + pqv*q_ ----
    float oA[8], oB[8];
#pragma unroll
    for (int d = 0; d < 8; ++d) {
        oA[d] = fmaf(pqv, qp[d], Pn * b_kv[64 + h8 + d]);
        oB[d] = 0.f;
    }
#pragma unroll
    for (int c = 0; c < 64; ++c) {
        const float* w = W_kv + (c << 7) + 64 + h8;
#pragma unroll
        for (int d = 0; d < 8; ++d) {
            if (c & 1) oB[d] = fmaf(y[c], w[d], oB[d]);
            else       oA[d] = fmaf(y[c], w[d], oA[d]);
        }
        if ((c & 15) == 15) __builtin_amdgcn_sched_barrier(0);
    }

    // ---- handoff through pre (aliased into smem), stride 33 ----
    __syncthreads();                        // all packed-tile reads complete
    float* pre = (float*)smem;              // [pixel][33]
#pragma unroll
    for (int d = 0; d < 8; ++d)
        pre[lane * 33 + (wv << 3) + d] = oA[d] + oB[d];
    __syncthreads();

    // ---- partial output projection over this block's 32 pre-channels ----
    const int j0 = wv << 4;
    float o2[16];
#pragma unroll
    for (int jj = 0; jj < 16; ++jj)
        o2[jj] = (hg == 0) ? b_proj[j0 + jj] : 0.f;
    int pb = lane * 33; LAUNDER(pb);
    const float* pl = pre + pb;
#pragma unroll
    for (int c = 0; c < 32; ++c) {
        float a = pl[c];
        const float* w = W_proj + ((hg * 32 + c) << 6) + j0;
#pragma unroll
        for (int jj = 0; jj < 16; ++jj) o2[jj] = fmaf(a, w[jj], o2[jj]);
        if ((c & 15) == 15) __builtin_amdgcn_sched_barrier(0);
    }
    float* ob = out + (size_t)bb * (64 * 64 * 64);
    const int pr = h0r + tr, pc = w0c + tc;
#pragma unroll
    for (int jj = 0; jj < 16; ++jj)
        unsafeAtomicAdd(&ob[((j0 + jj) << 12) + (pr << 6) + pc], o2[jj]);
}

extern "C" void kernel_launch(void* const* d_in, const int* in_sizes, int n_in,
                              void* d_out, int out_size, void* d_ws, size_t ws_size,
                              hipStream_t stream)
{
    const float* x      = (const float*)d_in[0];
    const float* W_qk   = (const float*)d_in[1];
    const float* b_qk   = (const float*)d_in[2];
    const float* W_kv   = (const float*)d_in[3];
    const float* b_kv   = (const float*)d_in[4];
    const float* W_proj = (const float*)d_in[5];
    const float* b_proj = (const float*)d_in[6];
    float* out = (float*)d_out;

    hipMemsetAsync(out, 0, (size_t)out_size * sizeof(float), stream);
    pix_attn_main<<<1024, 256, 0, stream>>>(x, W_qk, b_qk, W_kv, b_kv,
                                            W_proj, b_proj, out);
}